// Round 6
// baseline (394.668 us; speedup 1.0000x reference)
//
#include <hip/hip_runtime.h>
#include <hip/hip_bf16.h>
#include <cstdint>
#include <cstddef>

// Problem constants (B=1 implicit)
static constexpr int kT   = 1024;
static constexpr int kCV  = 8;
static constexpr int kDim = 2048;
static constexpr int kNH  = 32;
static constexpr int kHD  = 64;
static constexpr int kW   = 8;
static constexpr int kK   = 2048;   // inner dim of every GEMM

using bf16_t = __hip_bfloat16;

typedef __attribute__((ext_vector_type(8))) __bf16 bf16x8;
typedef __attribute__((ext_vector_type(4))) float  f32x4;

__device__ __forceinline__ float bf_bits_to_f32(unsigned short u) {
    union { unsigned int i; float f; } c;
    c.i = ((unsigned int)u) << 16;
    return c.f;
}

// ---------------------------------------------------------------------------
// Merged fp32 -> bf16 cast for all 6 inputs in ONE launch.
// ---------------------------------------------------------------------------
struct CastArgs {
    const float* src[6];
    bf16_t*      dst[6];
    int          cum[7];   // cumulative 8-elem chunk counts
};

__global__ void cast_all(CastArgs a, int total_chunks) {
    const int c = blockIdx.x * blockDim.x + threadIdx.x;
    if (c >= total_chunks) return;
    int r = 0;
#pragma unroll
    for (int i = 1; i <= 5; ++i) r += (c >= a.cum[i]) ? 1 : 0;
    const int local = c - a.cum[r];
    const float* s = a.src[r] + (size_t)local * 8;
    bf16_t*      d = a.dst[r] + (size_t)local * 8;
    const float4 lo = *reinterpret_cast<const float4*>(s);
    const float4 hi = *reinterpret_cast<const float4*>(s + 4);
    union { bf16_t h[8]; uint4 u; } o;
    o.h[0] = __float2bfloat16(lo.x); o.h[1] = __float2bfloat16(lo.y);
    o.h[2] = __float2bfloat16(lo.z); o.h[3] = __float2bfloat16(lo.w);
    o.h[4] = __float2bfloat16(hi.x); o.h[5] = __float2bfloat16(hi.y);
    o.h[6] = __float2bfloat16(hi.z); o.h[7] = __float2bfloat16(hi.w);
    *reinterpret_cast<uint4*>(d) = o.u;
}

// ---------------------------------------------------------------------------
// GEMM body: 128x128 tile of A[M,K] * Wt[N,K]^T, bf16 in, BK=64.
// XOR-swizzled LDS (R3: conflicts 8.4M -> 0).
// MODE 0: fp32 row-major C (p0, ldc=2048)
// MODE 1: kv head-major   — col<2048: kT[h][row][d]; else vT[h-32][row][d]
//         (h = col>>6, d = col&63; h uniform per 64-col wave tile)
// MODE 2: q  head-major   — qT[h][row][d]
// ---------------------------------------------------------------------------
template <int MODE>
__device__ __forceinline__ void gemm_body(const bf16_t* __restrict__ A,
                                          const bf16_t* __restrict__ Wt,
                                          void* __restrict__ p0,
                                          void* __restrict__ p1,
                                          int bm, int bn) {
    __shared__ bf16_t As[128 * 64];   // 16 KB
    __shared__ bf16_t Bs[128 * 64];   // 16 KB

    const int tid  = threadIdx.x;
    const int wave = tid >> 6;
    const int lane = tid & 63;
    const int l16  = lane & 15;
    const int quad = lane >> 4;
    const int wm   = (wave >> 1) * 64;
    const int wn   = (wave & 1) * 64;

    f32x4 acc[4][4];
#pragma unroll
    for (int i = 0; i < 4; ++i)
#pragma unroll
        for (int j = 0; j < 4; ++j) acc[i][j] = (f32x4)0.0f;

    // Staging: LDS chunk c = i*256 + tid, row = c>>3, slot jl = c&7;
    // global chunk j_g = jl ^ (row&7)  (swizzle within the 128B row segment).
    const int srow = tid >> 3;                       // 0..31
    const int jg   = (tid & 7) ^ (srow & 7);
    const bf16_t* gA = A  + (size_t)(bm + srow) * kK + jg * 8;
    const bf16_t* gB = Wt + (size_t)(bn + srow) * kK + jg * 8;

    for (int k0 = 0; k0 < kK; k0 += 64) {
#pragma unroll
        for (int i = 0; i < 4; ++i) {
            __builtin_amdgcn_global_load_lds(
                (const __attribute__((address_space(1))) void*)(gA + (size_t)i * 32 * kK + k0),
                (__attribute__((address_space(3))) void*)(As + i * 2048 + wave * 512),
                16, 0, 0);
            __builtin_amdgcn_global_load_lds(
                (const __attribute__((address_space(1))) void*)(gB + (size_t)i * 32 * kK + k0),
                (__attribute__((address_space(3))) void*)(Bs + i * 2048 + wave * 512),
                16, 0, 0);
        }
        __syncthreads();

#pragma unroll
        for (int ph = 0; ph < 2; ++ph) {
            bf16x8 af[4], bfr[4];
#pragma unroll
            for (int i = 0; i < 4; ++i) {
                const int jla = (ph * 4 + quad) ^ (l16 & 7);   // swizzled slot
                af[i]  = *reinterpret_cast<const bf16x8*>(
                    &As[(wm + i * 16 + l16) * 64 + jla * 8]);
                bfr[i] = *reinterpret_cast<const bf16x8*>(
                    &Bs[(wn + i * 16 + l16) * 64 + jla * 8]);
            }
#pragma unroll
            for (int i = 0; i < 4; ++i)
#pragma unroll
                for (int j = 0; j < 4; ++j)
                    acc[i][j] = __builtin_amdgcn_mfma_f32_16x16x32_bf16(
                        af[i], bfr[j], acc[i][j], 0, 0, 0);
        }
        __syncthreads();
    }

    // Epilogue. C/D layout: col = lane&15, row = quad*4 + reg  [m89]
#pragma unroll
    for (int i = 0; i < 4; ++i) {
#pragma unroll
        for (int rr = 0; rr < 4; ++rr) {
            const int row = bm + wm + i * 16 + quad * 4 + rr;
#pragma unroll
            for (int j = 0; j < 4; ++j) {
                const int col = bn + wn + j * 16 + l16;
                const float v = acc[i][j][rr];
                if constexpr (MODE == 0) {
                    ((float*)p0)[(size_t)row * 2048 + col] = v;
                } else if constexpr (MODE == 1) {
                    const int hl = col >> 6;        // wave-uniform
                    const int d  = col & 63;
                    bf16_t* dst = (hl < 32) ? (bf16_t*)p0 : (bf16_t*)p1;
                    const int h  = (hl < 32) ? hl : hl - 32;
                    dst[((size_t)h * (kT * kCV) + row) * 64 + d] =
                        __float2bfloat16(v);
                } else {
                    const int h = col >> 6;
                    const int d = col & 63;
                    ((bf16_t*)p0)[((size_t)h * kT + row) * 64 + d] =
                        __float2bfloat16(v);
                }
            }
        }
    }
}

// ---------------------------------------------------------------------------
// Fused projection kernel: blocks 0..2047 compute kv = chars @ [wk|wv]^T,
// written HEAD-MAJOR (kT/vT[h][t*8+c][64]); blocks 2048..2175 compute
// q = x @ wq^T written head-major (qT[h][t][64]).
// ---------------------------------------------------------------------------
__global__ __launch_bounds__(256, 3) void proj_kernel(
    const bf16_t* __restrict__ xb, const bf16_t* __restrict__ cb,
    const bf16_t* __restrict__ wqb, const bf16_t* __restrict__ wkvb,
    bf16_t* __restrict__ qTp, bf16_t* __restrict__ kTp,
    bf16_t* __restrict__ vTp) {
    const int bid = blockIdx.x;
    if (bid < 2048) {
        const int bm = (bid >> 5) * 128;
        const int bn = (bid & 31) * 128;
        gemm_body<1>(cb, wkvb, kTp, vTp, bm, bn);
    } else {
        const int t  = bid - 2048;
        const int bm = (t >> 4) * 128;
        const int bn = (t & 15) * 128;
        gemm_body<2>(xb, wqb, qTp, nullptr, bm, bn);
    }
}

// Output projection: out[1024,2048] = attn_out @ wo^T (fp32 out).
__global__ __launch_bounds__(256, 3) void out_gemm(
    const bf16_t* __restrict__ ob, const bf16_t* __restrict__ wob,
    float* __restrict__ out) {
    const int bm = (blockIdx.x >> 4) * 128;
    const int bn = (blockIdx.x & 15) * 128;
    gemm_body<0>(ob, wob, out, nullptr, bm, bn);
}

// ---------------------------------------------------------------------------
// Sliding-window attention, R6: one wave per (t,h), head-major k/v/q layout.
// Rows (t-7)*8 .. t*8+7 of kT[h] are CONSECUTIVE -> the k-read is a dense
// 8 KB block; each load instruction (fixed window j) covers a perfectly
// contiguous 1 KB: elems st*512 + lane*8. Lane = (kg = lane>>3 -> char c,
// dg = lane&7 -> dim octet); window = load index j. Key = j*8 + kg (relabel
// vs R5 is free: reductions are symmetric butterflies). Validity (st >= 0)
// is wave-uniform per j. RoPE skipped (exact cancellation); zero-padded
// windows give score exactly 0 in the softmax denom and v = 0 (reference
// zero-pad semantics).
// ---------------------------------------------------------------------------
__global__ __launch_bounds__(256) void attn_kernel(
    const bf16_t* __restrict__ qT,    // [NH][T][64]
    const bf16_t* __restrict__ kTp,   // [NH][T*CV][64]
    const bf16_t* __restrict__ vTp,   // [NH][T*CV][64]
    bf16_t* __restrict__ ob) {        // [T, 2048] row-major (out_gemm A)
    const int wid  = (blockIdx.x * 256 + threadIdx.x) >> 6;  // h*1024 + t
    const int t    = wid & (kT - 1);
    const int h    = wid >> 10;
    const int lane = threadIdx.x & 63;
    const int kg   = lane >> 3;   // char index c
    const int dg   = lane & 7;    // dim octet

    // q slice (8 lanes per dg share the address -> broadcast).
    union { uint4 u; unsigned short us[8]; } qu;
    qu.u = *reinterpret_cast<const uint4*>(
        qT + ((size_t)h * kT + t) * 64 + dg * 8);
    float qf[8];
#pragma unroll
    for (int i = 0; i < 8; ++i) qf[i] = bf_bits_to_f32(qu.us[i]);

    // Head-major dense loads: window j -> rows (t-7+j)*8 .. +7, 1 KB/instr.
    const bf16_t* kh = kTp + (size_t)h * (kT * kCV) * 64;
    const bf16_t* vh = vTp + (size_t)h * (kT * kCV) * 64;
    union { uint4 u; unsigned short us[8]; } kr[8], vr[8];
#pragma unroll
    for (int j = 0; j < 8; ++j) {
        const int st = t - (kW - 1) + j;
        const size_t a = (size_t)(st >= 0 ? st : 0) * 512 + lane * 8;
        kr[j].u = (st >= 0) ? *reinterpret_cast<const uint4*>(kh + a)
                            : make_uint4(0, 0, 0, 0);
        vr[j].u = (st >= 0) ? *reinterpret_cast<const uint4*>(vh + a)
                            : make_uint4(0, 0, 0, 0);
    }

    // Partial scores over this lane's dim octet, then dg-butterfly (1,2,4).
    float s[8];
#pragma unroll
    for (int j = 0; j < 8; ++j) {
        float acc = 0.0f;
#pragma unroll
        for (int i = 0; i < 8; ++i) acc += qf[i] * bf_bits_to_f32(kr[j].us[i]);
        s[j] = acc;
    }
#pragma unroll
    for (int off = 1; off <= 4; off <<= 1)
#pragma unroll
        for (int j = 0; j < 8; ++j) s[j] += __shfl_xor(s[j], off);
#pragma unroll
    for (int j = 0; j < 8; ++j) s[j] *= 0.125f;   // 1/sqrt(64)

    // Softmax over all 64 keys (8 local + kg-butterfly 8,16,32).
    float m = s[0];
#pragma unroll
    for (int j = 1; j < 8; ++j) m = fmaxf(m, s[j]);
#pragma unroll
    for (int off = 8; off <= 32; off <<= 1) m = fmaxf(m, __shfl_xor(m, off));
    float e[8], sum = 0.0f;
#pragma unroll
    for (int j = 0; j < 8; ++j) { e[j] = __expf(s[j] - m); sum += e[j]; }
#pragma unroll
    for (int off = 8; off <= 32; off <<= 1) sum += __shfl_xor(sum, off);
    const float inv = 1.0f / sum;

    // PV: this lane's 8 keys x its dim octet, then kg-butterfly.
    float o[8];
#pragma unroll
    for (int i = 0; i < 8; ++i) o[i] = 0.0f;
#pragma unroll
    for (int j = 0; j < 8; ++j) {
        const float p = e[j] * inv;
#pragma unroll
        for (int i = 0; i < 8; ++i) o[i] += p * bf_bits_to_f32(vr[j].us[i]);
    }
#pragma unroll
    for (int off = 8; off <= 32; off <<= 1)
#pragma unroll
        for (int i = 0; i < 8; ++i) o[i] += __shfl_xor(o[i], off);

    if (kg == 0) {   // lanes 0..7 store one contiguous 128B row segment
        union { bf16_t hh[8]; uint4 u; } ov;
#pragma unroll
        for (int i = 0; i < 8; ++i) ov.hh[i] = __float2bfloat16(o[i]);
        *reinterpret_cast<uint4*>(&ob[(size_t)t * kDim + h * kHD + dg * 8]) = ov.u;
    }
}

// ---------------------------------------------------------------------------
extern "C" void kernel_launch(void* const* d_in, const int* in_sizes, int n_in,
                              void* d_out, int out_size, void* d_ws,
                              size_t ws_size, hipStream_t stream) {
    const float* x     = (const float*)d_in[0];
    const float* chars = (const float*)d_in[1];
    const float* wq    = (const float*)d_in[2];
    const float* wk    = (const float*)d_in[3];
    const float* wv    = (const float*)d_in[4];
    const float* wo    = (const float*)d_in[5];
    float* out = (float*)d_out;

    // Workspace carve-up (~132 MiB total).
    char* p = (char*)d_ws;
    bf16_t* xb   = (bf16_t*)p; p += (size_t)kT * kDim * 2;            // 4 MB
    bf16_t* cb   = (bf16_t*)p; p += (size_t)kT * kCV * kDim * 2;      // 32 MB
    bf16_t* wqb  = (bf16_t*)p; p += (size_t)kDim * kDim * 2;          // 8 MB
    bf16_t* wkvb = (bf16_t*)p; p += (size_t)2 * kDim * kDim * 2;      // 16 MB
    bf16_t* wob  = (bf16_t*)p; p += (size_t)kDim * kDim * 2;          // 8 MB
    bf16_t* qTp  = (bf16_t*)p; p += (size_t)kT * kDim * 2;            // 4 MB
    bf16_t* kTp  = (bf16_t*)p; p += (size_t)kT * kCV * kDim * 2;      // 32 MB
    bf16_t* vTp  = (bf16_t*)p; p += (size_t)kT * kCV * kDim * 2;      // 32 MB
    bf16_t* ob   = (bf16_t*)p; p += (size_t)kT * kDim * 2;            // 4 MB

    // One cast launch for all six tensors.
    CastArgs ca;
    ca.src[0] = x;     ca.dst[0] = xb;
    ca.src[1] = chars; ca.dst[1] = cb;
    ca.src[2] = wq;    ca.dst[2] = wqb;
    ca.src[3] = wk;    ca.dst[3] = wkvb;
    ca.src[4] = wv;    ca.dst[4] = wkvb + (size_t)kDim * kDim;
    ca.src[5] = wo;    ca.dst[5] = wob;
    const int sizes[6] = {kT * kDim, kT * kCV * kDim, kDim * kDim,
                          kDim * kDim, kDim * kDim, kDim * kDim};
    int cum = 0;
    ca.cum[0] = 0;
    for (int i = 0; i < 6; ++i) { cum += sizes[i] / 8; ca.cum[i + 1] = cum; }
    cast_all<<<dim3((cum + 255) / 256), dim3(256), 0, stream>>>(ca, cum);

    // Fused k|v (N=4096) + q projections, head-major epilogue.
    proj_kernel<<<dim3(2176), dim3(256), 0, stream>>>(xb, cb, wqb, wkvb,
                                                      qTp, kTp, vTp);

    // Sliding-window attention: 32768 waves (1 per (t,h)), 4 waves/block.
    attn_kernel<<<dim3(kT * kNH / 4), dim3(256), 0, stream>>>(qTp, kTp, vTp, ob);

    // Output projection (fp32 out).
    out_gemm<<<dim3(128), dim3(256), 0, stream>>>(ob, wob, out);
}